// Round 1
// baseline (399.255 us; speedup 1.0000x reference)
//
#include <hip/hip_runtime.h>
#include <math.h>

#define N_IMG 128
#define C_DIM 128
#define K_CL  64
#define S_PIX 4096
#define PB    8                 // blocks per image
#define SPB   (S_PIX/PB)        // 512 pixels per block
#define SB    64                // chunk pixels
#define NCHUNK (SPB/SB)         // 8
#define XS_P  132               // xs row stride (floats)
#define AT_P  68                // at row stride (floats)

// ---------------- kernel 0: transpose conv_w [K][C] -> wt [C][K] ----------------
__global__ void k_transpose_w(const float* __restrict__ w, float* __restrict__ wt) {
    int i = blockIdx.x * 256 + threadIdx.x;     // 8192 elements
    int k = i >> 7, c = i & 127;
    wt[c * K_CL + k] = w[i];
}

// ---------------- kernel 1: fused norm -> logits -> softmax -> vlad partial ------
__global__ __launch_bounds__(256, 3)
void k_main(const float* __restrict__ x,      // [N][C][S]
            const float* __restrict__ wt,     // [C][K]
            const float* __restrict__ bias,   // [K]
            float* __restrict__ vlad,         // [N][K][C] accumulator (= d_out)
            float* __restrict__ asum)         // [N][K]
{
    __shared__ float xs[SB][XS_P];  // raw x tile, [s][c]
    __shared__ float at[SB][AT_P];  // a' = a*rnorm tile, [s][k]
    __shared__ float red[SB][4];    // softmax cross-quarter reductions

    const int tid = threadIdx.x;
    const int n   = blockIdx.x / PB;
    const int sp  = blockIdx.x % PB;

    // phase-a identity: pixel sA, k-quarter q (16 k's each)
    const int sA   = tid & 63;
    const int q    = tid >> 6;
    const int kq16 = __builtin_amdgcn_readfirstlane(q << 4);  // wave-uniform

    // phase-b identity: s-parity group g, k-octet kh, c-quads at co*4 and 64+co*4
    const int g  = tid >> 7;
    const int wv = tid & 127;
    const int kh = wv >> 4;
    const int co = wv & 15;

    float acc[64];
    #pragma unroll
    for (int i = 0; i < 64; ++i) acc[i] = 0.f;
    float asum_acc[16];
    #pragma unroll
    for (int i = 0; i < 16; ++i) asum_acc[i] = 0.f;

    // bias for this quarter (uniform index -> scalar loads)
    float rb[16];
    #pragma unroll
    for (int j = 0; j < 16; ++j) rb[j] = bias[kq16 + j];

    const float* xbase = x + (size_t)n * ((size_t)C_DIM * S_PIX) + sp * SPB;

    for (int ch = 0; ch < NCHUNK; ++ch) {
        __syncthreads();   // previous chunk's phase-b readers done before overwrite
        const float* xp = xbase + ch * SB + sA;

        // ---- phase a: raw dots over all c for 16 k's; sumsq; stage raw x ----
        float dot[16];
        #pragma unroll
        for (int j = 0; j < 16; ++j) dot[j] = 0.f;
        float ss = 0.f;

        #pragma unroll 2
        for (int c0 = 0; c0 < C_DIM; c0 += 4) {
            float xv[4];
            #pragma unroll
            for (int u = 0; u < 4; ++u) xv[u] = xp[(size_t)(c0 + u) * S_PIX];
            #pragma unroll
            for (int u = 0; u < 4; ++u) {
                ss = fmaf(xv[u], xv[u], ss);
                const float* wrow = wt + (c0 + u) * K_CL + kq16;  // uniform addr
                #pragma unroll
                for (int j = 0; j < 16; ++j) dot[j] = fmaf(xv[u], wrow[j], dot[j]);
            }
            if (((c0 >> 2) & 3) == q) {   // distribute xs writes across waves
                float4 t4; t4.x = xv[0]; t4.y = xv[1]; t4.z = xv[2]; t4.w = xv[3];
                *(float4*)&xs[sA][c0] = t4;
            }
        }

        // ---- softmax over 64 clusters (4-way quarter exchange via LDS) ----
        float rnorm = 1.0f / fmaxf(sqrtf(ss), 1e-12f);
        #pragma unroll
        for (int j = 0; j < 16; ++j) dot[j] = fmaf(dot[j], rnorm, rb[j]);
        float mx = dot[0];
        #pragma unroll
        for (int j = 1; j < 16; ++j) mx = fmaxf(mx, dot[j]);
        red[sA][q] = mx;
        __syncthreads();
        float gm = fmaxf(fmaxf(red[sA][0], red[sA][1]), fmaxf(red[sA][2], red[sA][3]));
        __syncthreads();
        float sm = 0.f;
        #pragma unroll
        for (int j = 0; j < 16; ++j) { dot[j] = __expf(dot[j] - gm); sm += dot[j]; }
        red[sA][q] = sm;
        __syncthreads();
        float inv = 1.0f / (red[sA][0] + red[sA][1] + red[sA][2] + red[sA][3]);
        #pragma unroll
        for (int j4 = 0; j4 < 16; j4 += 4) {
            float a0 = dot[j4+0]*inv, a1 = dot[j4+1]*inv, a2 = dot[j4+2]*inv, a3 = dot[j4+3]*inv;
            asum_acc[j4+0] += a0; asum_acc[j4+1] += a1;
            asum_acc[j4+2] += a2; asum_acc[j4+3] += a3;
            float4 t4; t4.x = a0*rnorm; t4.y = a1*rnorm; t4.z = a2*rnorm; t4.w = a3*rnorm;
            *(float4*)&at[sA][kq16 + j4] = t4;   // a' carries rnorm; xs stays raw
        }
        __syncthreads();   // xs + at visible

        // ---- phase b: vlad_partial[k][c] += a'[s][k] * x_raw[s][c] ----
        #pragma unroll 2
        for (int t = 0; t < SB/2; ++t) {
            int s = (t << 1) + g;
            float4 a0 = *(const float4*)&at[s][kh*8];
            float4 a1 = *(const float4*)&at[s][kh*8 + 4];
            float4 x0 = *(const float4*)&xs[s][co*4];
            float4 x1 = *(const float4*)&xs[s][64 + co*4];
            float av[8] = {a0.x,a0.y,a0.z,a0.w,a1.x,a1.y,a1.z,a1.w};
            float xv[8] = {x0.x,x0.y,x0.z,x0.w,x1.x,x1.y,x1.z,x1.w};
            #pragma unroll
            for (int kk = 0; kk < 8; ++kk)
                #pragma unroll
                for (int cc = 0; cc < 8; ++cc)
                    acc[kk*8+cc] = fmaf(av[kk], xv[cc], acc[kk*8+cc]);
        }
    }

    // ---- cross-group (s-parity) reduce via LDS, then global atomics ----
    __syncthreads();
    float* redv = &xs[0][0];   // reuse xs (8448 floats >= 8192)
    if (g == 1) {
        #pragma unroll
        for (int i = 0; i < 64; ++i) redv[wv*64 + i] = acc[i];
    }
    __syncthreads();
    if (g == 0) {
        float* vb = vlad + (size_t)n * (K_CL * C_DIM);
        #pragma unroll
        for (int kk = 0; kk < 8; ++kk) {
            int k = kh*8 + kk;
            #pragma unroll
            for (int cc = 0; cc < 8; ++cc) {
                int c = (cc < 4) ? (co*4 + cc) : (64 + co*4 + cc - 4);
                atomicAdd(&vb[k*C_DIM + c], acc[kk*8+cc] + redv[wv*64 + kk*8+cc]);
            }
        }
    }

    // ---- asum: wave butterfly reduce (64 lanes share q), one atomic per k ----
    #pragma unroll
    for (int j = 0; j < 16; ++j) {
        float v = asum_acc[j];
        v += __shfl_xor(v, 32); v += __shfl_xor(v, 16); v += __shfl_xor(v, 8);
        v += __shfl_xor(v, 4);  v += __shfl_xor(v, 2);  v += __shfl_xor(v, 1);
        asum_acc[j] = v;
    }
    if ((tid & 63) == 0) {
        #pragma unroll
        for (int j = 0; j < 16; ++j)
            atomicAdd(&asum[n*K_CL + kq16 + j], asum_acc[j]);
    }
}

// ---------------- kernel 2: subtract a-sum*centroid, intra-norm, global norm ----
__global__ __launch_bounds__(256)
void k_final(float* __restrict__ vlad,          // [N][K*C] in/out (= d_out)
             const float* __restrict__ asum,    // [N][K]
             const float* __restrict__ cent)    // [K][C]
{
    __shared__ float v[K_CL * 132];
    __shared__ float red[K_CL][4];
    __shared__ float rin[K_CL];
    __shared__ float rtot_s;
    const int tid = threadIdx.x;
    const int n   = blockIdx.x;
    float* vb = vlad + (size_t)n * (K_CL * C_DIM);
    const float* as = asum + n * K_CL;

    for (int i = tid; i < K_CL*C_DIM; i += 256) {
        int k = i >> 7, c = i & 127;
        v[k*132 + c] = vb[i] - as[k] * cent[i];
    }
    __syncthreads();
    {
        int k = tid >> 2, p = tid & 3;     // 4 partials per k, c = 4u+p (bank-safe)
        float s2 = 0.f;
        #pragma unroll
        for (int u = 0; u < 32; ++u) { float t = v[k*132 + (u<<2) + p]; s2 = fmaf(t, t, s2); }
        red[k][p] = s2;
    }
    __syncthreads();
    if (tid < K_CL) {
        float s2 = red[tid][0] + red[tid][1] + red[tid][2] + red[tid][3];
        float r  = 1.0f / fmaxf(sqrtf(s2), 1e-12f);
        rin[tid] = r;
        red[tid][0] = s2 * r * r;          // ||intra-normalized row||^2
    }
    __syncthreads();
    if (tid < 64) {
        float t = red[tid][0];
        t += __shfl_xor(t, 32); t += __shfl_xor(t, 16); t += __shfl_xor(t, 8);
        t += __shfl_xor(t, 4);  t += __shfl_xor(t, 2);  t += __shfl_xor(t, 1);
        if (tid == 0) rtot_s = 1.0f / fmaxf(sqrtf(t), 1e-12f);
    }
    __syncthreads();
    float rt = rtot_s;
    for (int i = tid; i < K_CL*C_DIM; i += 256) {
        vb[i] = v[(i>>7)*132 + (i&127)] * rin[i>>7] * rt;
    }
}

extern "C" void kernel_launch(void* const* d_in, const int* in_sizes, int n_in,
                              void* d_out, int out_size, void* d_ws, size_t ws_size,
                              hipStream_t stream) {
    const float* x    = (const float*)d_in[0];   // [N][C][H][W]
    const float* w    = (const float*)d_in[1];   // [K][C]
    const float* b    = (const float*)d_in[2];   // [K]
    const float* cent = (const float*)d_in[3];   // [K][C]
    float* out  = (float*)d_out;                 // [N][K*C], reused as accumulator
    float* wt   = (float*)d_ws;                  // [C][K]   (32 KB)
    float* asum = (float*)d_ws + (C_DIM*K_CL);   // [N][K]   (32 KB)

    hipMemsetAsync(out,  0, (size_t)N_IMG * K_CL * C_DIM * sizeof(float), stream);
    hipMemsetAsync(asum, 0, (size_t)N_IMG * K_CL * sizeof(float), stream);

    k_transpose_w<<<(K_CL*C_DIM)/256, 256, 0, stream>>>(w, wt);
    k_main<<<N_IMG * PB, 256, 0, stream>>>(x, wt, b, out, asum);
    k_final<<<N_IMG, 256, 0, stream>>>(out, asum, cent);
}

// Round 2
// 214.669 us; speedup vs baseline: 1.8599x; 1.8599x over previous
//
#include <hip/hip_runtime.h>
#include <math.h>

#define N_IMG 128
#define C_DIM 128
#define K_CL  64
#define S_PIX 4096
#define PB    8                 // blocks per image
#define SPB   (S_PIX/PB)        // 512 pixels per block
#define CHK   64                // pixels per chunk
#define NCHK  (SPB/CHK)         // 8
#define SROW  72                // a' row stride (bf16 elems), 144B rows (16B-aligned)

typedef __attribute__((ext_vector_type(8))) short bf16x8;
typedef __attribute__((ext_vector_type(4))) float f32x4;

__device__ __forceinline__ unsigned short f2bf(float v) {
    unsigned u = __float_as_uint(v);
    unsigned r = u + 0x7fffu + ((u >> 16) & 1u);   // RN-even
    return (unsigned short)(r >> 16);
}
__device__ __forceinline__ float bf2f(unsigned short h) {
    return __uint_as_float(((unsigned)h) << 16);
}

// ---- kernel 0: W [K][C] fp32 -> pre-fragmented hi/lo bf16 A-fragments ----
// layout: wf[hl][m][t][lane][j] ; k = 16m+(lane&15), c = 32t+8*(lane>>4)+j
__global__ void k_prep(const float* __restrict__ w, unsigned short* __restrict__ wf) {
    int i = blockIdx.x * 256 + threadIdx.x;          // 8192
    int j = i & 7, l = (i >> 3) & 63, t = (i >> 9) & 3, m = (i >> 11) & 3;
    int k = 16*m + (l & 15);
    int c = 32*t + ((l >> 4) << 3) + j;
    float v = w[k * C_DIM + c];
    unsigned short h = f2bf(v);
    wf[i]        = h;
    wf[8192 + i] = f2bf(v - bf2f(h));
}

// ---- kernel 1: fused GEMM1(MFMA) -> softmax -> GEMM2(MFMA), split-bf16 ----
__global__ __launch_bounds__(256, 3)
void k_main(const float* __restrict__ x,              // [N][C][S]
            const unsigned short* __restrict__ wf,    // [2][16][64][8] bf16 bits
            const float* __restrict__ bias,           // [K]
            float* __restrict__ vlad,                 // [N][K][C] accumulator (= d_out)
            float* __restrict__ asum)                 // [N][K]
{
    __shared__ f32x4 lWv[2048];                       // 32KB: W fragments hi/lo
    __shared__ f32x4 aSv[1152];                       // 18KB: a' tile [2][64][SROW] bf16
    unsigned short* lW = (unsigned short*)lWv;
    unsigned short* aS = (unsigned short*)aSv;

    const int tid  = threadIdx.x;
    const int lane = tid & 63;
    const int wid  = tid >> 6;
    const int lc   = lane & 15;
    const int g    = lane >> 4;

    const int n  = blockIdx.x / PB;
    const int sp = blockIdx.x % PB;
    const float* xn = x + (size_t)n * (C_DIM * S_PIX) + sp * SPB;

    // stage W fragments into LDS (32KB, once per block)
    #pragma unroll
    for (int it = 0; it < 8; ++it)
        lWv[it*256 + tid] = ((const f32x4*)wf)[it*256 + tid];

    // per-lane bias for the 16 k's this lane owns in D-layout
    float bb[16];
    #pragma unroll
    for (int m = 0; m < 4; ++m)
        #pragma unroll
        for (int jj = 0; jj < 4; ++jj)
            bb[m*4+jj] = bias[16*m + 4*g + jj];

    f32x4 accV[4][2];
    #pragma unroll
    for (int m = 0; m < 4; ++m) { accV[m][0] = (f32x4)0.f; accV[m][1] = (f32x4)0.f; }
    float asum_acc[16];
    #pragma unroll
    for (int i = 0; i < 16; ++i) asum_acc[i] = 0.f;

    __syncthreads();

    for (int ch = 0; ch < NCHK; ++ch) {
        // ================= Phase A: GEMM1 + softmax (wave's 16-pixel slice) ==========
        const int sA = ch*CHK + wid*16 + lc;          // pixel within block range
        f32x4 accL[4];
        #pragma unroll
        for (int m = 0; m < 4; ++m) accL[m] = (f32x4)0.f;
        float ss = 0.f;

        #pragma unroll
        for (int t = 0; t < 4; ++t) {
            const float* xp = xn + (size_t)(32*t + 8*g) * S_PIX + sA;
            float xv[8];
            #pragma unroll
            for (int j = 0; j < 8; ++j) xv[j] = xp[(size_t)j * S_PIX];
            bf16x8 bh, blo;
            #pragma unroll
            for (int j = 0; j < 8; ++j) {
                ss = fmaf(xv[j], xv[j], ss);
                unsigned short h = f2bf(xv[j]);
                bh[j]  = (short)h;
                blo[j] = (short)f2bf(xv[j] - bf2f(h));
            }
            #pragma unroll
            for (int m = 0; m < 4; ++m) {
                bf16x8 ah = *(const bf16x8*)&lW[((m*4 + t)*64 + lane)*8];
                bf16x8 al = *(const bf16x8*)&lW[((16 + m*4 + t)*64 + lane)*8];
                accL[m] = __builtin_amdgcn_mfma_f32_16x16x32_bf16(ah, bh,  accL[m], 0,0,0);
                accL[m] = __builtin_amdgcn_mfma_f32_16x16x32_bf16(ah, blo, accL[m], 0,0,0);
                accL[m] = __builtin_amdgcn_mfma_f32_16x16x32_bf16(al, bh,  accL[m], 0,0,0);
            }
        }
        // rnorm: lane's 32 c's + 4-lane butterfly (lanes sharing lc) -> all 128 c
        ss += __shfl_xor(ss, 16); ss += __shfl_xor(ss, 32);
        float rnorm = 1.0f / fmaxf(sqrtf(ss), 1e-12f);

        // softmax over k=64 (16 regs in-lane + 4-lane butterfly)
        float e[16]; float mx = -1e30f;
        #pragma unroll
        for (int m = 0; m < 4; ++m)
            #pragma unroll
            for (int jj = 0; jj < 4; ++jj) {
                float t2 = fmaf(accL[m][jj], rnorm, bb[m*4+jj]);
                e[m*4+jj] = t2;
                mx = fmaxf(mx, t2);
            }
        mx = fmaxf(mx, __shfl_xor(mx, 16)); mx = fmaxf(mx, __shfl_xor(mx, 32));
        float sm = 0.f;
        #pragma unroll
        for (int i = 0; i < 16; ++i) { e[i] = __expf(e[i] - mx); sm += e[i]; }
        sm += __shfl_xor(sm, 16); sm += __shfl_xor(sm, 32);
        float inv = 1.0f / sm;

        // a' = a*rnorm -> hi/lo bf16 -> LDS [k][s_loc]; accumulate asum (raw a)
        const int sl = wid*16 + lc;
        #pragma unroll
        for (int m = 0; m < 4; ++m)
            #pragma unroll
            for (int jj = 0; jj < 4; ++jj) {
                float a = e[m*4+jj] * inv;
                asum_acc[m*4+jj] += a;
                float ap = a * rnorm;
                unsigned short h = f2bf(ap);
                int k = 16*m + 4*g + jj;
                aS[k*SROW + sl]               = h;
                aS[K_CL*SROW + k*SROW + sl]   = f2bf(ap - bf2f(h));
            }
        __syncthreads();   // a' tile complete

        // ================= Phase B: GEMM2 (wave's 32-c slice) ========================
        const int cq = wid * 32;
        #pragma unroll
        for (int ks = 0; ks < 2; ++ks) {
            bf16x8 Ah[4], Al[4];
            #pragma unroll
            for (int m = 0; m < 4; ++m) {
                int off = (16*m + lc) * SROW + ks*32 + 8*g;
                Ah[m] = *(const bf16x8*)&aS[off];
                Al[m] = *(const bf16x8*)&aS[K_CL*SROW + off];
            }
            #pragma unroll
            for (int nn = 0; nn < 2; ++nn) {
                const float* xp = xn + (size_t)(cq + nn*16 + lc) * S_PIX
                                + ch*CHK + ks*32 + 8*g;
                float4 f0 = *(const float4*)xp;
                float4 f1 = *(const float4*)(xp + 4);
                float xv[8] = {f0.x,f0.y,f0.z,f0.w,f1.x,f1.y,f1.z,f1.w};
                bf16x8 xh, xl;
                #pragma unroll
                for (int j = 0; j < 8; ++j) {
                    unsigned short h = f2bf(xv[j]);
                    xh[j] = (short)h;
                    xl[j] = (short)f2bf(xv[j] - bf2f(h));
                }
                #pragma unroll
                for (int m = 0; m < 4; ++m) {
                    accV[m][nn] = __builtin_amdgcn_mfma_f32_16x16x32_bf16(Ah[m], xh, accV[m][nn], 0,0,0);
                    accV[m][nn] = __builtin_amdgcn_mfma_f32_16x16x32_bf16(Ah[m], xl, accV[m][nn], 0,0,0);
                    accV[m][nn] = __builtin_amdgcn_mfma_f32_16x16x32_bf16(Al[m], xh, accV[m][nn], 0,0,0);
                }
            }
        }
        __syncthreads();   // aS free for next chunk
    }

    // ---- epilogue: vlad partials -> global atomics ----
    float* vb = vlad + (size_t)n * (K_CL * C_DIM);
    const int cq = wid * 32;
    #pragma unroll
    for (int m = 0; m < 4; ++m)
        #pragma unroll
        for (int nn = 0; nn < 2; ++nn)
            #pragma unroll
            for (int jj = 0; jj < 4; ++jj)
                atomicAdd(&vb[(16*m + 4*g + jj)*C_DIM + cq + nn*16 + lc],
                          accV[m][nn][jj]);

    // ---- asum: 16-lane butterfly (lanes sharing g), then atomics ----
    #pragma unroll
    for (int i = 0; i < 16; ++i) {
        float v = asum_acc[i];
        v += __shfl_xor(v, 1); v += __shfl_xor(v, 2);
        v += __shfl_xor(v, 4); v += __shfl_xor(v, 8);
        asum_acc[i] = v;
    }
    if (lc == 0) {
        #pragma unroll
        for (int m = 0; m < 4; ++m)
            #pragma unroll
            for (int jj = 0; jj < 4; ++jj)
                atomicAdd(&asum[n*K_CL + 16*m + 4*g + jj], asum_acc[m*4+jj]);
    }
}

// ---- kernel 2: subtract a-sum*centroid, intra-norm, global norm ----
__global__ __launch_bounds__(256)
void k_final(float* __restrict__ vlad,          // [N][K*C] in/out (= d_out)
             const float* __restrict__ asum,    // [N][K]
             const float* __restrict__ cent)    // [K][C]
{
    __shared__ float v[K_CL * 132];
    __shared__ float red[K_CL][4];
    __shared__ float rin[K_CL];
    __shared__ float rtot_s;
    const int tid = threadIdx.x;
    const int n   = blockIdx.x;
    float* vb = vlad + (size_t)n * (K_CL * C_DIM);
    const float* as = asum + n * K_CL;

    for (int i = tid; i < K_CL*C_DIM; i += 256) {
        int k = i >> 7, c = i & 127;
        v[k*132 + c] = vb[i] - as[k] * cent[i];
    }
    __syncthreads();
    {
        int k = tid >> 2, p = tid & 3;
        float s2 = 0.f;
        #pragma unroll
        for (int u = 0; u < 32; ++u) { float t = v[k*132 + (u<<2) + p]; s2 = fmaf(t, t, s2); }
        red[k][p] = s2;
    }
    __syncthreads();
    if (tid < K_CL) {
        float s2 = red[tid][0] + red[tid][1] + red[tid][2] + red[tid][3];
        float r  = 1.0f / fmaxf(sqrtf(s2), 1e-12f);
        rin[tid] = r;
        red[tid][0] = s2 * r * r;
    }
    __syncthreads();
    if (tid < 64) {
        float t = red[tid][0];
        t += __shfl_xor(t, 32); t += __shfl_xor(t, 16); t += __shfl_xor(t, 8);
        t += __shfl_xor(t, 4);  t += __shfl_xor(t, 2);  t += __shfl_xor(t, 1);
        if (tid == 0) rtot_s = 1.0f / fmaxf(sqrtf(t), 1e-12f);
    }
    __syncthreads();
    float rt = rtot_s;
    for (int i = tid; i < K_CL*C_DIM; i += 256) {
        vb[i] = v[(i>>7)*132 + (i&127)] * rin[i>>7] * rt;
    }
}

extern "C" void kernel_launch(void* const* d_in, const int* in_sizes, int n_in,
                              void* d_out, int out_size, void* d_ws, size_t ws_size,
                              hipStream_t stream) {
    const float* x    = (const float*)d_in[0];   // [N][C][H][W]
    const float* w    = (const float*)d_in[1];   // [K][C]
    const float* b    = (const float*)d_in[2];   // [K]
    const float* cent = (const float*)d_in[3];   // [K][C]
    float* out = (float*)d_out;                           // [N][K*C]
    unsigned short* wf = (unsigned short*)d_ws;           // 2*8192 bf16 = 32KB
    float* asum = (float*)((char*)d_ws + 32768);          // [N][K] = 32KB

    hipMemsetAsync(out,  0, (size_t)N_IMG * K_CL * C_DIM * sizeof(float), stream);
    hipMemsetAsync(asum, 0, (size_t)N_IMG * K_CL * sizeof(float), stream);

    k_prep<<<32, 256, 0, stream>>>(w, wf);
    k_main<<<N_IMG * PB, 256, 0, stream>>>(x, wf, b, out, asum);
    k_final<<<N_IMG, 256, 0, stream>>>(out, asum, cent);
}